// Round 7
// baseline (1192.062 us; speedup 1.0000x reference)
//
#include <hip/hip_runtime.h>
#include <stdint.h>

#define BB 8
#define NN 8192
#define NPOINT 1024
#define NSAMPLE 32
#define XS 104   // x row stride in bf16 elems (cols: 0..63 feat, 64..66 xyz, 67..95 zero)
#define HS 72    // h / w2 / w3 row stride in bf16 elems (cols 0..63 used)

typedef short short8 __attribute__((ext_vector_type(8)));
typedef float floatx4 __attribute__((ext_vector_type(4)));

__device__ __forceinline__ unsigned short f2bf(float f) {
    unsigned u = __float_as_uint(f);
    unsigned r = u + 0x7FFFu + ((u >> 16) & 1u);   // RNE to bf16
    return (unsigned short)(r >> 16);
}

__device__ __forceinline__ unsigned long long u64max(unsigned long long a,
                                                     unsigned long long b) {
    return (a > b) ? a : b;
}

template <int CTRL, int RMASK>
__device__ __forceinline__ unsigned long long dpp_max_step(unsigned long long key) {
    int lo = (int)(unsigned int)(key & 0xffffffffull);
    int hi = (int)(unsigned int)(key >> 32);
    int tlo = __builtin_amdgcn_update_dpp(0, lo, CTRL, RMASK, 0xF, true);
    int thi = __builtin_amdgcn_update_dpp(0, hi, CTRL, RMASK, 0xF, true);
    unsigned long long t = ((unsigned long long)(unsigned int)thi << 32) |
                           (unsigned long long)(unsigned int)tlo;
    return u64max(key, t);
}

__device__ __forceinline__ unsigned long long dpp_wave_max(unsigned long long key) {
    key = dpp_max_step<0x111, 0xF>(key);  // row_shr:1
    key = dpp_max_step<0x112, 0xF>(key);  // row_shr:2
    key = dpp_max_step<0x114, 0xF>(key);  // row_shr:4
    key = dpp_max_step<0x118, 0xF>(key);  // row_shr:8
    key = dpp_max_step<0x142, 0xA>(key);  // row_bcast:15
    key = dpp_max_step<0x143, 0xC>(key);  // row_bcast:31
    return key;
}

// ---------------------------------------------------------------------------
// Kernel 1: farthest point sampling. One block (256 threads, 32 pts/thread,
// 1 wave/SIMD) per batch. launch_bounds(256,1) lets the allocator keep the
// full ~160-reg working set (R3's 132-cap spilled; R5's 2 waves/SIMD only
// added barrier lockstep — kernel is per-wave-latency bound).
// Bit-exact vs numpy: d2 = ((dx*dx + dy*dy) + dz*dz) via __f*_rn; argmax
// ties -> lowest index. TWO independent (bd,bi) chains (even/odd elements)
// halve the serial cmp->cndmask chain; exact tie-break restored via u64
// (bits<<32)|~gi key max. One barrier/iter, double-buffered wred[2][4].
// ---------------------------------------------------------------------------
__global__ __launch_bounds__(256, 1) void fps_kernel(const float* __restrict__ xyz,
                                                     float* __restrict__ new_xyz) {
    __shared__ float sx[NN];
    __shared__ float sy[NN];
    __shared__ float sz[NN];
    __shared__ __align__(16) unsigned long long wred[2][4];

    const int b = blockIdx.x;
    const int t = threadIdx.x;
    const int lane = t & 63;
    const int wv = t >> 6;                  // 4 waves
    const float* base = xyz + (size_t)b * NN * 3;

    float px[32], py[32], pz[32], dist[32];
#pragma unroll
    for (int i = 0; i < 32; ++i) {
        int p = t + (i << 8);               // coalesced glb, conflict-free LDS
        float x = base[p * 3 + 0];
        float y = base[p * 3 + 1];
        float z = base[p * 3 + 2];
        sx[p] = x; sy[p] = y; sz[p] = z;
        px[i] = x; py[i] = y; pz[i] = z;
        dist[i] = 1e10f;                    // f32(10000000000.0) exact
    }
    __syncthreads();

    float lx = sx[0], ly = sy[0], lz = sz[0];
    float* outb = new_xyz + (size_t)b * NPOINT * 3;
    if (t == 0) { outb[0] = lx; outb[1] = ly; outb[2] = lz; }

    for (int j = 1; j < NPOINT; ++j) {
        float bd0 = -1.0f, bd1 = -1.0f;
        int bi0 = 0, bi1 = 1;
#pragma unroll
        for (int i = 0; i < 32; i += 2) {
            {   // even chain
                float dx = __fsub_rn(px[i], lx);
                float dy = __fsub_rn(py[i], ly);
                float dz = __fsub_rn(pz[i], lz);
                float d2 = __fadd_rn(__fadd_rn(__fmul_rn(dx, dx), __fmul_rn(dy, dy)),
                                     __fmul_rn(dz, dz));
                float dd = fminf(dist[i], d2);
                dist[i] = dd;
                bool gt = dd > bd0;         // strict: lowest even i on ties
                bd0 = gt ? dd : bd0;
                bi0 = gt ? i : bi0;
            }
            {   // odd chain
                float dx = __fsub_rn(px[i + 1], lx);
                float dy = __fsub_rn(py[i + 1], ly);
                float dz = __fsub_rn(pz[i + 1], lz);
                float d2 = __fadd_rn(__fadd_rn(__fmul_rn(dx, dx), __fmul_rn(dy, dy)),
                                     __fmul_rn(dz, dz));
                float dd = fminf(dist[i + 1], d2);
                dist[i + 1] = dd;
                bool gt = dd > bd1;         // strict: lowest odd i on ties
                bd1 = gt ? dd : bd1;
                bi1 = gt ? (i + 1) : bi1;
            }
        }
        // merge chains + cross-thread via u64 keys; ~gi makes equal-dist
        // compare pick the SMALLER global index (numpy argmax semantics).
        unsigned long long key0 =
            ((unsigned long long)__float_as_uint(bd0) << 32) |
            (unsigned long long)(~(unsigned int)(t + (bi0 << 8)));
        unsigned long long key1 =
            ((unsigned long long)__float_as_uint(bd1) << 32) |
            (unsigned long long)(~(unsigned int)(t + (bi1 << 8)));
        unsigned long long key = u64max(key0, key1);
        key = dpp_wave_max(key);
        if (lane == 63) wred[j & 1][wv] = key;
        __syncthreads();
        int cur;
        {
            const unsigned long long* wr = wred[j & 1];
            ulonglong2 p01 = *(const ulonglong2*)&wr[0];  // 2x b128 broadcast
            ulonglong2 p23 = *(const ulonglong2*)&wr[2];
            unsigned long long m = u64max(u64max(p01.x, p01.y),
                                          u64max(p23.x, p23.y));
            cur = (int)(~(unsigned int)(m & 0xffffffffull));
        }
        lx = sx[cur]; ly = sy[cur]; lz = sz[cur];          // LDS broadcast
        if (t == 0) {                                      // fire-and-forget
            outb[j * 3 + 0] = lx;
            outb[j * 3 + 1] = ly;
            outb[j * 3 + 2] = lz;
        }
    }
}

// ---------------------------------------------------------------------------
// Kernel 2: FUSED ball query + gather + 3-layer MLP (bf16 MFMA 16x16x32) +
// max-pool. Block = 256 thr = 4 waves = 4 centroids (128 pts). Wave w does
// its own ball query into s_gi[w*32..] (first NSAMPLE in-radius, ascending,
// padded with first hit — bit-exact __f*_rn math), then the R6 MFMA MLP.
// Weights staged BEFORE the scan so stores overlap scan latency.
// ---------------------------------------------------------------------------
__global__ __launch_bounds__(256) void fused_bq_mlp_kernel(
    const float* __restrict__ xyz, const float* __restrict__ features,
    const float* __restrict__ w1, const float* __restrict__ b1,
    const float* __restrict__ w2, const float* __restrict__ b2,
    const float* __restrict__ w3, const float* __restrict__ b3,
    const float* __restrict__ new_xyz, float* __restrict__ out_feat) {
    __shared__ __align__(16) unsigned short s_x[128 * XS];    // 26624 B; later h2[128][HS]
    __shared__ __align__(16) unsigned short s_h[128 * HS];    // 18432 B
    __shared__ __align__(16) unsigned short s_w12[11264];     // w1[64][XS]@0, w2[64][HS]@6656; later w3[128][HS]@0
    __shared__ int s_gi[128];

    const int t = threadIdx.x;
    const int lane = t & 63;
    const int w = t >> 6;
    const int col = lane & 15;
    const int quad = lane >> 4;
    const int blk = blockIdx.x;
    const int bi = blk >> 8;              // 256 blocks per batch

    // ---- stage w1, w2 (independent of ball query) ----
    {
        int o = t >> 2, part = t & 3;
        const float* w1r = w1 + o * 67;
#pragma unroll
        for (int i = 0; i < 26; ++i) {
            int c = part * 26 + i;
            float v = 0.0f;
            if (c < 64) v = w1r[3 + c];           // permuted: feats first
            else if (c < 67) v = w1r[c - 64];     // then xyz cols
            s_w12[o * XS + c] = f2bf(v);
        }
        const float* w2r = w2 + o * 64 + part * 16;
#pragma unroll
        for (int i = 0; i < 8; ++i) {
            unsigned pk = (unsigned)f2bf(w2r[2 * i]) |
                          ((unsigned)f2bf(w2r[2 * i + 1]) << 16);
            *(unsigned*)&s_w12[6656 + o * HS + part * 16 + 2 * i] = pk;
        }
    }

    // ---- ball query: wave w -> centroid (blk*4 + w) ----
    {
        const int g = (blk << 2) + w;
        const float R2 = (float)(0.4 * 0.4);      // 0.15999999642f, matches ref
        const float cx = new_xyz[g * 3 + 0];
        const float cy = new_xyz[g * 3 + 1];
        const float cz = new_xyz[g * 3 + 2];
        const float* base = xyz + (size_t)bi * NN * 3;

        int have = 0;
        for (int chunk = 0; chunk < (NN / 64) && have < NSAMPLE; ++chunk) {
            int p = (chunk << 6) + lane;
            float dx = __fsub_rn(cx, base[p * 3 + 0]);
            float dy = __fsub_rn(cy, base[p * 3 + 1]);
            float dz = __fsub_rn(cz, base[p * 3 + 2]);
            float d2 = __fadd_rn(__fadd_rn(__fmul_rn(dx, dx), __fmul_rn(dy, dy)),
                                 __fmul_rn(dz, dz));
            bool in = d2 < R2;
            unsigned long long m = __ballot(in);
            int pre = __popcll(m & ((1ull << lane) - 1ull));
            int slot = have + pre;
            if (in && slot < NSAMPLE) s_gi[w * NSAMPLE + slot] = p;
            have += (int)__popcll(m);
        }
        if (lane < NSAMPLE) {
            int first = s_gi[w * NSAMPLE];        // centroid always hits: have>=1
            int v = (lane < have) ? s_gi[w * NSAMPLE + lane] : first;
            s_gi[w * NSAMPLE + lane] = v;
        }
    }
    __syncthreads();

    // ---- gather x = [feat(64) | xyz_rel(3) | zeros] in bf16 ----
    {
        int k = t >> 1, half = t & 1;
        int row = s_gi[k];
        const float4* frow =
            (const float4*)(features + ((size_t)bi * NN + row) * 64) + half * 8;
        unsigned short* xr = &s_x[k * XS + half * 32];
#pragma unroll
        for (int i = 0; i < 8; ++i) {
            float4 v = frow[i];
            unsigned lo = (unsigned)f2bf(v.x) | ((unsigned)f2bf(v.y) << 16);
            unsigned hi = (unsigned)f2bf(v.z) | ((unsigned)f2bf(v.w) << 16);
            *(uint2*)(xr + i * 4) = make_uint2(lo, hi);
        }
    }
    if (t < 128) {
        int k = t;
        int row = s_gi[k];
        int gg = (blk << 2) + (k >> 5);
        const float* pr = xyz + ((size_t)bi * NN + row) * 3;
        const float* cr = new_xyz + (size_t)gg * 3;
        s_x[k * XS + 64] = f2bf(pr[0] - cr[0]);
        s_x[k * XS + 65] = f2bf(pr[1] - cr[1]);
        s_x[k * XS + 66] = f2bf(pr[2] - cr[2]);
        s_x[k * XS + 67] = 0;
        unsigned* z = (unsigned*)&s_x[k * XS + 68];
#pragma unroll
        for (int i = 0; i < 14; ++i) z[i] = 0;        // cols 68..95
    }
    __syncthreads();

    const int mbase = w * 32;

    // ---- Layer 1: [128 x 96] x [96 -> 64] ----
    floatx4 acc[2][4] = {};
    for (int kk = 0; kk < 3; ++kk) {
        short8 a0 = *(const short8*)&s_x[(mbase + col) * XS + kk * 32 + quad * 8];
        short8 a1 = *(const short8*)&s_x[(mbase + 16 + col) * XS + kk * 32 + quad * 8];
#pragma unroll
        for (int nt = 0; nt < 4; ++nt) {
            short8 b = *(const short8*)&s_w12[(nt * 16 + col) * XS + kk * 32 + quad * 8];
            acc[0][nt] = __builtin_amdgcn_mfma_f32_16x16x32_bf16(a0, b, acc[0][nt], 0, 0, 0);
            acc[1][nt] = __builtin_amdgcn_mfma_f32_16x16x32_bf16(a1, b, acc[1][nt], 0, 0, 0);
        }
    }
#pragma unroll
    for (int nt = 0; nt < 4; ++nt) {
        float bb = b1[nt * 16 + col];
#pragma unroll
        for (int mt = 0; mt < 2; ++mt)
#pragma unroll
            for (int r = 0; r < 4; ++r) {
                float v = fmaxf(acc[mt][nt][r] + bb, 0.0f);
                s_h[(mbase + mt * 16 + quad * 4 + r) * HS + nt * 16 + col] = f2bf(v);
            }
    }
    __syncthreads();

    // ---- Layer 2: [128 x 64] x [64 -> 64], h2 -> s_x region ----
    floatx4 acc2[2][4] = {};
    for (int kk = 0; kk < 2; ++kk) {
        short8 a0 = *(const short8*)&s_h[(mbase + col) * HS + kk * 32 + quad * 8];
        short8 a1 = *(const short8*)&s_h[(mbase + 16 + col) * HS + kk * 32 + quad * 8];
#pragma unroll
        for (int nt = 0; nt < 4; ++nt) {
            short8 b = *(const short8*)&s_w12[6656 + (nt * 16 + col) * HS + kk * 32 + quad * 8];
            acc2[0][nt] = __builtin_amdgcn_mfma_f32_16x16x32_bf16(a0, b, acc2[0][nt], 0, 0, 0);
            acc2[1][nt] = __builtin_amdgcn_mfma_f32_16x16x32_bf16(a1, b, acc2[1][nt], 0, 0, 0);
        }
    }
    unsigned short* s_h2 = s_x;  // x dead after L1
#pragma unroll
    for (int nt = 0; nt < 4; ++nt) {
        float bb = b2[nt * 16 + col];
#pragma unroll
        for (int mt = 0; mt < 2; ++mt)
#pragma unroll
            for (int r = 0; r < 4; ++r) {
                float v = fmaxf(acc2[mt][nt][r] + bb, 0.0f);
                s_h2[(mbase + mt * 16 + quad * 4 + r) * HS + nt * 16 + col] = f2bf(v);
            }
    }
    __syncthreads();   // h2 complete; all w2 reads done

    // ---- stage w3 [128][HS] over w1/w2 ----
    {
        int o = t >> 1, half = t & 1;
        const float* w3r = w3 + o * 64 + half * 32;
#pragma unroll
        for (int i = 0; i < 16; ++i) {
            unsigned pk = (unsigned)f2bf(w3r[2 * i]) |
                          ((unsigned)f2bf(w3r[2 * i + 1]) << 16);
            *(unsigned*)&s_w12[o * HS + half * 32 + 2 * i] = pk;
        }
    }
    __syncthreads();

    // ---- Layer 3: [128 x 64] x [64 -> 128], fused k-maxpool + bias + relu ----
    floatx4 c3[2][8] = {};
    for (int kk = 0; kk < 2; ++kk) {
        short8 a0 = *(const short8*)&s_h2[(mbase + col) * HS + kk * 32 + quad * 8];
        short8 a1 = *(const short8*)&s_h2[(mbase + 16 + col) * HS + kk * 32 + quad * 8];
#pragma unroll
        for (int nt = 0; nt < 8; ++nt) {
            short8 b = *(const short8*)&s_w12[(nt * 16 + col) * HS + kk * 32 + quad * 8];
            c3[0][nt] = __builtin_amdgcn_mfma_f32_16x16x32_bf16(a0, b, c3[0][nt], 0, 0, 0);
            c3[1][nt] = __builtin_amdgcn_mfma_f32_16x16x32_bf16(a1, b, c3[1][nt], 0, 0, 0);
        }
    }
    {
        int gg = (blk << 2) + w;
        float* ob = out_feat + (size_t)bi * (128 * 1024) + (gg & 1023);
#pragma unroll
        for (int nt = 0; nt < 8; ++nt) {
            float m = fmaxf(fmaxf(fmaxf(c3[0][nt][0], c3[0][nt][1]),
                                  fmaxf(c3[0][nt][2], c3[0][nt][3])),
                            fmaxf(fmaxf(c3[1][nt][0], c3[1][nt][1]),
                                  fmaxf(c3[1][nt][2], c3[1][nt][3])));
            m = fmaxf(m, __shfl_xor(m, 16));
            m = fmaxf(m, __shfl_xor(m, 32));
            if (lane < 16) {
                float v = fmaxf(m + b3[nt * 16 + lane], 0.0f);
                ob[(size_t)(nt * 16 + lane) * 1024] = v;
            }
        }
    }
}

extern "C" void kernel_launch(void* const* d_in, const int* in_sizes, int n_in,
                              void* d_out, int out_size, void* d_ws, size_t ws_size,
                              hipStream_t stream) {
    const float* xyz      = (const float*)d_in[0];
    const float* features = (const float*)d_in[1];
    const float* w1       = (const float*)d_in[2];
    const float* b1       = (const float*)d_in[3];
    const float* w2       = (const float*)d_in[4];
    const float* b2       = (const float*)d_in[5];
    const float* w3       = (const float*)d_in[6];
    const float* b3       = (const float*)d_in[7];

    float* out      = (float*)d_out;
    float* new_xyz  = out;                         // B*NPOINT*3
    float* out_feat = out + BB * NPOINT * 3;       // B*128*NPOINT

    fps_kernel<<<BB, 256, 0, stream>>>(xyz, new_xyz);
    fused_bq_mlp_kernel<<<(BB * NPOINT) / 4, 256, 0, stream>>>(
        xyz, features, w1, b1, w2, b2, w3, b3, new_xyz, out_feat);
}